// Round 18
// baseline (192.372 us; speedup 1.0000x reference)
//
#include <hip/hip_runtime.h>

#define L_RES 2000
#define DF 54
#define WIN 7

typedef short bf16x8 __attribute__((ext_vector_type(8)));
typedef float f32x4 __attribute__((ext_vector_type(4)));
typedef unsigned short ushort8v __attribute__((ext_vector_type(8)));

__device__ __forceinline__ unsigned short f2bf(float f) {
    unsigned int u = __float_as_uint(f);
    unsigned int r = (u + 0x7FFFu + ((u >> 16) & 1u)) >> 16;
    return (unsigned short)r;
}
__device__ __forceinline__ float bf2f(unsigned short h) {
    return __uint_as_float(((unsigned int)h) << 16);
}
// async global->LDS, 16B per lane; LDS dest = wave-uniform base + lane*16
__device__ __forceinline__ void gload16(const unsigned short* g, unsigned short* l) {
    __builtin_amdgcn_global_load_lds(
        (const __attribute__((address_space(1))) void*)g,
        (__attribute__((address_space(3))) void*)l, 16, 0, 0);
}

// ---------------- prep: B2T (bert, blocks 0..767) + W1b bf16 (blocks 768..1791) ----------------
__global__ __launch_bounds__(256) void prep_w(const float* __restrict__ Wb,
                                              unsigned short* __restrict__ B2T,
                                              const float* __restrict__ W1,
                                              unsigned short* __restrict__ W1b) {
    int bid = blockIdx.x;
    if (bid < 768) {
        int idx = bid * 256 + threadIdx.x;   // 64*3072
        int n = idx / 3072, col = idx % 3072;
        int seg = col >> 10, k = col & 1023;
        unsigned short r = 0;
        if (n < DF) {
            float v = Wb[(size_t)k * DF + n];
            unsigned short hi = f2bf(v);
            r = (seg < 2) ? hi : f2bf(v - bf2f(hi));
        }
        B2T[idx] = r;
    } else {
        int idx = (bid - 768) * 256 + threadIdx.x;   // 1024*256
        int m = idx >> 8, j = idx & 255;
        W1b[idx] = (m < 972) ? f2bf(W1[(size_t)m * 256 + j]) : (unsigned short)0;
    }
}

// ---------------- W2re[c*256+n][j] = bf16(W2[(c*256+j)*256+n]) : per-c 256x256 transpose ----------------
__global__ __launch_bounds__(256) void w2re_build(const float* __restrict__ W2,
                                                  unsigned short* __restrict__ W2re) {
    __shared__ float tile[32][33];
    int c = blockIdx.z;
    const float* src = W2 + (size_t)c * 65536;      // [256 j][256 n]
    unsigned short* dst = W2re + (size_t)c * 65536; // [256 n][256 j]
    int j0 = blockIdx.x * 32, n0 = blockIdx.y * 32;
    int cc = threadIdx.x % 32, r0 = threadIdx.x / 32;
    #pragma unroll
    for (int rr = 0; rr < 4; ++rr) {
        int r = r0 + rr * 8;
        tile[r][cc] = src[(size_t)(j0 + r) * 256 + n0 + cc];
    }
    __syncthreads();
    #pragma unroll
    for (int rr = 0; rr < 4; ++rr) {
        int r = r0 + rr * 8;
        dst[(size_t)(n0 + r) * 256 + j0 + cc] = f2bf(tile[cc][r]);
    }
}

// ---------------- bcombp[c][n] = sum_j b1[j] * W2[(c*256+j)*256+n]  (fp32) ----------------
__global__ __launch_bounds__(256) void bcombp_build(const float* __restrict__ b1,
                                                    const float* __restrict__ W2,
                                                    float* __restrict__ bcombp) {
    int c = blockIdx.x, n = threadIdx.x;
    float s = 0.f;
    for (int j = 0; j < 256; ++j)
        s = fmaf(b1[j], W2[(size_t)(c * 256 + j) * 256 + n], s);
    bcombp[c * 256 + n] = s;
}

// ---------------- gemmW: P2 = packed-frag Wcomb. out[k][n] = sum_j W1b[k&1023][j]*W2re[c*256+n][j] ----------------
// grid 256 (m-tiles of 128 over k=0..32767), 256 thr, 4 waves 1m x 4n, K=256, direct global frags.
__global__ __launch_bounds__(256) void gemmW(const unsigned short* __restrict__ W1b,
                                             const unsigned short* __restrict__ W2re,
                                             unsigned short* __restrict__ P2) {
    int t = threadIdx.x, w = t >> 6, lane = t & 63;
    int bid = blockIdx.x;
    int c = bid >> 3, mloc = (bid & 7) * 128;
    int k0g = bid * 128;
    int arow = lane & 15, kgrp = lane >> 4;
    f32x4 acc[8][4];
    #pragma unroll
    for (int mi = 0; mi < 8; ++mi)
        #pragma unroll
        for (int ni = 0; ni < 4; ++ni) acc[mi][ni] = (f32x4)(0.f);
    #pragma unroll
    for (int ks = 0; ks < 4; ++ks) {
        #pragma unroll
        for (int kk = 0; kk < 2; ++kk) {
            int kc = ks * 64 + kk * 32 + kgrp * 8;
            bf16x8 af[8], bfr[4];
            #pragma unroll
            for (int mi = 0; mi < 8; ++mi)
                af[mi] = *(const bf16x8*)&W1b[(size_t)(mloc + mi * 16 + arow) * 256 + kc];
            #pragma unroll
            for (int ni = 0; ni < 4; ++ni) {
                int n = w * 64 + ni * 16 + arow;
                bfr[ni] = *(const bf16x8*)&W2re[(size_t)(c * 256 + n) * 256 + kc];
            }
            #pragma unroll
            for (int mi = 0; mi < 8; ++mi)
                #pragma unroll
                for (int ni = 0; ni < 4; ++ni)
                    acc[mi][ni] = __builtin_amdgcn_mfma_f32_16x16x32_bf16(af[mi], bfr[ni], acc[mi][ni], 0, 0, 0);
        }
    }
    // epilogue: packed-frag stores. k0 = k0g+mi*16+kgrp*4 gives 4 consecutive k (r=0..3)
    #pragma unroll
    for (int ni = 0; ni < 4; ++ni) {
        int n = w * 64 + ni * 16 + arow;
        int nb = n >> 4, ar = n & 15;
        #pragma unroll
        for (int mi = 0; mi < 8; ++mi) {
            int k0 = k0g + mi * 16 + kgrp * 4;
            int zp = k0 >> 11, ksz = (k0 >> 6) & 31, kk2 = (k0 >> 5) & 1;
            int kg = (k0 >> 3) & 3, e0 = k0 & 7;   // 0 or 4
            size_t idx = (((size_t)(zp * 16 + nb) * 64 + ksz * 2 + kk2) * 512)
                         + (kg * 16 + ar) * 8 + e0;
            unsigned int lo = (unsigned int)f2bf(acc[mi][ni][0]) | ((unsigned int)f2bf(acc[mi][ni][1]) << 16);
            unsigned int hi = (unsigned int)f2bf(acc[mi][ni][2]) | ((unsigned int)f2bf(acc[mi][ni][3]) << 16);
            *(unsigned int*)&P2[idx] = lo;
            *(unsigned int*)&P2[idx + 2] = hi;
        }
    }
}

// ---------------- bert fused: MFMA GEMM M=2048 N=64 K=3072, A = [hi | lo | hi] in-register ----------------
__global__ __launch_bounds__(256) void bert_mfma(const float* __restrict__ beft,
                                                 const unsigned short* __restrict__ B2T,
                                                 float* __restrict__ bpart) {
    __shared__ unsigned short ldsA[128 * 64];
    __shared__ unsigned short ldsB[64 * 64];
    int t = threadIdx.x, w = t >> 6, lane = t & 63;
    int m0 = blockIdx.x * 128;
    int z = blockIdx.y;
    int koff = z * 768;
    int wr = w >> 1, wc = w & 1;
    int arow = lane & 15, kgrp = lane >> 4;

    int cj[4], aD[4];
    const float* aF[4];
    bool vald[4];
    #pragma unroll
    for (int j = 0; j < 4; ++j) {
        int s = j * 256 + t, r = s >> 3, c = s & 7;
        cj[j] = c;
        aD[j] = r * 64 + ((c ^ (r & 7)) * 8);
        vald[j] = (m0 + r) < L_RES;
        aF[j] = beft + (size_t)(vald[j] ? (m0 + r) : 0) * 1024;
    }
    const unsigned short* bS[2]; int bD[2];
    #pragma unroll
    for (int j = 0; j < 2; ++j) {
        int s = j * 256 + t, r = s >> 3, c = s & 7;
        bS[j] = B2T + koff + (size_t)r * 3072 + c * 8;
        bD[j] = r * 64 + ((c ^ (r & 7)) * 8);
    }
    f32x4 acc[4][2];
    #pragma unroll
    for (int mi = 0; mi < 4; ++mi)
        #pragma unroll
        for (int ni = 0; ni < 2; ++ni) acc[mi][ni] = (f32x4)(0.f);

    f32x4 va0[4], va1[4];
    ushort8v vb[2];
    #pragma unroll
    for (int j = 0; j < 4; ++j) {
        int bc = (koff + cj[j] * 8) & 1023;
        va0[j] = *(const f32x4*)(aF[j] + bc);
        va1[j] = *(const f32x4*)(aF[j] + bc + 4);
    }
    #pragma unroll
    for (int j = 0; j < 2; ++j) vb[j] = *(const ushort8v*)(bS[j]);

    for (int ks = 0; ks < 12; ++ks) {
        __syncthreads();
        #pragma unroll
        for (int j = 0; j < 4; ++j) {
            int x = koff + ks * 64 + cj[j] * 8;
            int seg = x >> 10;
            ushort8v v;
            #pragma unroll
            for (int e = 0; e < 8; ++e) {
                float val = (e < 4) ? va0[j][e] : va1[j][e - 4];
                if (!vald[j]) val = 0.f;
                unsigned short hi = f2bf(val);
                v[e] = (seg == 1) ? f2bf(val - bf2f(hi)) : hi;   // A: seg1 = lo
            }
            *(ushort8v*)&ldsA[aD[j]] = v;
        }
        #pragma unroll
        for (int j = 0; j < 2; ++j) *(ushort8v*)&ldsB[bD[j]] = vb[j];
        __syncthreads();
        if (ks + 1 < 12) {
            #pragma unroll
            for (int j = 0; j < 4; ++j) {
                int bc = (koff + (ks + 1) * 64 + cj[j] * 8) & 1023;
                va0[j] = *(const f32x4*)(aF[j] + bc);
                va1[j] = *(const f32x4*)(aF[j] + bc + 4);
            }
            #pragma unroll
            for (int j = 0; j < 2; ++j) vb[j] = *(const ushort8v*)(bS[j] + (ks + 1) * 64);
        }
        #pragma unroll
        for (int kk = 0; kk < 2; ++kk) {
            int chunk = kk * 4 + kgrp;
            bf16x8 af[4], bfr[2];
            #pragma unroll
            for (int mi = 0; mi < 4; ++mi) {
                int rl = wr * 64 + mi * 16 + arow;
                af[mi] = *(const bf16x8*)&ldsA[rl * 64 + ((chunk ^ (rl & 7)) * 8)];
            }
            #pragma unroll
            for (int ni = 0; ni < 2; ++ni) {
                int rl = wc * 32 + ni * 16 + arow;
                bfr[ni] = *(const bf16x8*)&ldsB[rl * 64 + ((chunk ^ (rl & 7)) * 8)];
            }
            #pragma unroll
            for (int mi = 0; mi < 4; ++mi)
                #pragma unroll
                for (int ni = 0; ni < 2; ++ni)
                    acc[mi][ni] = __builtin_amdgcn_mfma_f32_16x16x32_bf16(af[mi], bfr[ni], acc[mi][ni], 0, 0, 0);
        }
    }
    #pragma unroll
    for (int ni = 0; ni < 2; ++ni) {
        int n = wc * 32 + ni * 16 + arow;
        #pragma unroll
        for (int mi = 0; mi < 4; ++mi)
            #pragma unroll
            for (int r = 0; r < 4; ++r) {
                int m = m0 + wr * 64 + mi * 16 + kgrp * 4 + r;
                bpart[((size_t)z * 2048 + m) * 64 + n] = acc[mi][ni][r];
            }
    }
}

// ---------------- window gather (+ fused bert reduce) + attn x2 + concat ----------------
__device__ __forceinline__ void attn_layer(const float (*in)[DF], float (*out)[DF],
                                           float (*s)[WIN][WIN],
                                           const float* __restrict__ g,
                                           const float* __restrict__ b,
                                           float* mm, float* vv, int t) {
    for (int idx = t; idx < 3 * WIN * WIN; idx += 64) {
        int h = idx / 49, r = idx % 49, q = r / WIN, k = r % WIN;
        float sum = 0.f;
        #pragma unroll
        for (int d = 0; d < 18; ++d) sum = fmaf(in[q][h * 18 + d], in[k][h * 18 + d], sum);
        s[h][q][k] = sum;
    }
    __syncthreads();
    for (int idx = t; idx < 3 * WIN; idx += 64) {
        int h = idx / WIN, q = idx % WIN;
        float mx = s[h][q][0];
        #pragma unroll
        for (int k = 1; k < WIN; ++k) mx = fmaxf(mx, s[h][q][k]);
        float e[WIN], sum = 0.f;
        #pragma unroll
        for (int k = 0; k < WIN; ++k) { e[k] = expf(s[h][q][k] - mx); sum += e[k]; }
        float inv = 1.f / sum;
        #pragma unroll
        for (int k = 0; k < WIN; ++k) s[h][q][k] = e[k] * inv;
    }
    __syncthreads();
    for (int idx = t; idx < WIN * DF; idx += 64) {
        int q = idx / DF, c = idx % DF, h = c / 18;
        float sum = 0.f;
        #pragma unroll
        for (int k = 0; k < WIN; ++k) sum = fmaf(s[h][q][k], in[k][c], sum);
        out[q][c] = sum;
    }
    __syncthreads();
    for (int q = t; q < WIN; q += 64) {
        float m = 0.f;
        for (int c = 0; c < DF; ++c) m += out[q][c];
        m *= (1.f / DF);
        float v = 0.f;
        for (int c = 0; c < DF; ++c) { float d0 = out[q][c] - m; v = fmaf(d0, d0, v); }
        v *= (1.f / DF);
        mm[q] = m; vv[q] = rsqrtf(v + 1e-5f);
    }
    __syncthreads();
    for (int idx = t; idx < WIN * DF; idx += 64) {
        int q = idx / DF, c = idx % DF;
        out[q][c] = (out[q][c] - mm[q]) * vv[q] * g[c] + b[c];
    }
    __syncthreads();
}

__global__ __launch_bounds__(64) void window_attn(const float* __restrict__ bpart,
                                                  const float* __restrict__ bb,
                                                  const float* __restrict__ g1,
                                                  const float* __restrict__ b1,
                                                  const float* __restrict__ g2,
                                                  const float* __restrict__ b2,
                                                  float* __restrict__ cat) {
    int l = blockIdx.x;
    int t = threadIdx.x;
    __shared__ float w[WIN][DF], o1[WIN][DF], o2[WIN][DF];
    __shared__ float s[3][WIN][WIN];
    __shared__ float mm[WIN], vv[WIN];
    bool boundary = (l <= WIN) || (l + WIN >= L_RES);
    for (int idx = t; idx < WIN * DF; idx += 64) {
        int j = idx / DF, d = idx % DF;
        float v = 0.f;
        if (!boundary || j == 0) {
            int lsrc = boundary ? l : (l - 4 + j);
            v = bb[d];
            #pragma unroll
            for (int z = 0; z < 4; ++z) v += bpart[((size_t)z * 2048 + lsrc) * 64 + d];
        }
        w[j][d] = v;
    }
    __syncthreads();
    attn_layer(w, o1, s, g1, b1, mm, vv, t);
    attn_layer(o1, o2, s, g2, b2, mm, vv, t);
    for (int idx = t; idx < WIN * DF; idx += 64) {
        int j = idx / DF, d = idx % DF;
        cat[(size_t)l * 756 + j * 108 + d] = w[j][d];
        cat[(size_t)l * 756 + j * 108 + DF + d] = o2[j][d];
    }
}

// ---------------- conv+pool -> Apool[2000][32768] bf16 (row l, col c*1024+m) ----------------
__global__ __launch_bounds__(256) void conv_pool(
        const float* __restrict__ cat,
        const float* __restrict__ c1w, const float* __restrict__ c1b,
        const float* __restrict__ pa_p,
        const float* __restrict__ c2w, const float* __restrict__ c2b,
        const float* __restrict__ c3w, const float* __restrict__ c3b,
        unsigned short* __restrict__ Ap) {
    int bid = blockIdx.x;
    int b = bid >> 2;
    int ch0 = (bid & 3) * 8;
    int l0 = b * 4;
    int t = threadIdx.x;
    __shared__ float catl[4 * 756];
    for (int i = t; i < 3024; i += 256) catl[i] = cat[(size_t)l0 * 756 + i];
    __syncthreads();
    float pa = pa_p[0];
    unsigned short* base = Ap + (size_t)b * 128 * 1024;
    int res = t >> 6, dp = t & 63;
    if (dp < 54) {
        int d0 = dp * 2;
        const float* cr = catl + res * 756;
        float colA[WIN], colB[WIN];
        #pragma unroll
        for (int h = 0; h < WIN; ++h) {
            colA[h] = cr[h * 108 + d0];
            colB[h] = cr[h * 108 + d0 + 1];
        }
        for (int c = ch0; c < ch0 + 8; ++c) {             // wave-uniform channel loop
            unsigned short* Arow = base + (size_t)(res * 32 + c) * 1024;
            {   // branch 1: k=3, prelu, pool3 -> 5 outputs
                float w0 = c1w[c * 3], w1 = c1w[c * 3 + 1], w2 = c1w[c * 3 + 2];
                float bb = c1b[c];
                float vA[WIN], vB[WIN];
                #pragma unroll
                for (int h = 0; h < WIN; ++h) {
                    float sA = bb, sB = bb;
                    if (h >= 1) { sA = fmaf(w0, colA[h - 1], sA); sB = fmaf(w0, colB[h - 1], sB); }
                    sA = fmaf(w1, colA[h], sA); sB = fmaf(w1, colB[h], sB);
                    if (h <= 5) { sA = fmaf(w2, colA[h + 1], sA); sB = fmaf(w2, colB[h + 1], sB); }
                    vA[h] = sA >= 0.f ? sA : pa * sA;
                    vB[h] = sB >= 0.f ? sB : pa * sB;
                }
                #pragma unroll
                for (int p = 0; p < 5; ++p) {
                    unsigned int ua = f2bf(fmaxf(fmaxf(vA[p], vA[p + 1]), vA[p + 2]));
                    unsigned int ub = f2bf(fmaxf(fmaxf(vB[p], vB[p + 1]), vB[p + 2]));
                    *(unsigned int*)&Arow[p * 108 + d0] = ua | (ub << 16);
                }
            }
            {   // branch 2: k=5, relu, pool5 -> 3 outputs
                float wg[5], bb = c2b[c];
                #pragma unroll
                for (int x = 0; x < 5; ++x) wg[x] = c2w[c * 5 + x];
                float vA[WIN], vB[WIN];
                #pragma unroll
                for (int h = 0; h < WIN; ++h) {
                    float sA = bb, sB = bb;
                    #pragma unroll
                    for (int x = 0; x < 5; ++x) {
                        int hh = h + x - 2;
                        if (hh >= 0 && hh <= 6) {
                            sA = fmaf(wg[x], colA[hh], sA);
                            sB = fmaf(wg[x], colB[hh], sB);
                        }
                    }
                    vA[h] = fmaxf(sA, 0.f);
                    vB[h] = fmaxf(sB, 0.f);
                }
                #pragma unroll
                for (int p = 0; p < 3; ++p) {
                    float ma = vA[p], mb = vB[p];
                    #pragma unroll
                    for (int r = 1; r < 5; ++r) { ma = fmaxf(ma, vA[p + r]); mb = fmaxf(mb, vB[p + r]); }
                    unsigned int ua = f2bf(ma), ub = f2bf(mb);
                    *(unsigned int*)&Arow[540 + p * 108 + d0] = ua | (ub << 16);
                }
            }
            {   // branch 3: k=7, relu, pool7 -> 1 output
                float wg[7], bb = c3b[c];
                #pragma unroll
                for (int x = 0; x < 7; ++x) wg[x] = c3w[c * 7 + x];
                float ma = 0.f, mb = 0.f;
                #pragma unroll
                for (int h = 0; h < WIN; ++h) {
                    float sA = bb, sB = bb;
                    #pragma unroll
                    for (int x = 0; x < 7; ++x) {
                        int hh = h + x - 3;
                        if (hh >= 0 && hh <= 6) {
                            sA = fmaf(wg[x], colA[hh], sA);
                            sB = fmaf(wg[x], colB[hh], sB);
                        }
                    }
                    ma = fmaxf(ma, sA);
                    mb = fmaxf(mb, sB);
                }
                unsigned int ua = f2bf(fmaxf(ma, 0.f)), ub = f2bf(fmaxf(mb, 0.f));
                *(unsigned int*)&Arow[864 + d0] = ua | (ub << 16);
            }
        }
    }
    // zero K-pad cols 972..1023 for this block's 32 rows
    for (int i = t; i < 832; i += 256) {
        int r = i / 26, q = i - r * 26;
        int res2 = r >> 3, c2 = ch0 + (r & 7);
        *(unsigned int*)&base[(size_t)(res2 * 32 + c2) * 1024 + 972 + q * 2] = 0u;
    }
}

// ---------------- gemmC: part[z] = Apool[.,zK] @ Wcomb[zK,.] ; grid 256 = 16m x 8z x 2nh ----------------
// 256 thr, 4 waves (1m x 4n over 128-col n-half), C[128x128]/block, K=4096 (64 K-steps).
// A dbuf LDS via gload_lds (pre-swizzled source); B from P2 packed frags (contiguous 16B/lane).
__global__ __launch_bounds__(256, 2) void gemmC(const unsigned short* __restrict__ A,
                                                const unsigned short* __restrict__ P2,
                                                float* __restrict__ part) {
    __shared__ unsigned short ldsA[2][128 * 64];
    int t = threadIdx.x, w = t >> 6, lane = t & 63;
    int bid = blockIdx.x;
    int nh = bid & 1, z = (bid >> 1) & 7, mt = bid >> 4;
    long m0 = (long)mt * 128;
    long kbase = (long)z * 4096;
    int arow = lane & 15, kgrp = lane >> 4;
    int ra = lane >> 3, cc = lane & 7;
    int csw = (cc ^ ra) * 8;                     // pre-swizzled source column

    const unsigned short* gA[4]; int rb[4];
    #pragma unroll
    for (int j = 0; j < 4; ++j) {
        int rbase = j * 32 + w * 8;
        long row = m0 + rbase + ra;
        if (row >= L_RES) row = 0;               // clamp OOB tail rows
        gA[j] = A + row * 32768 + kbase + csw;
        rb[j] = rbase * 64;
    }
    f32x4 acc[8][2];
    #pragma unroll
    for (int mi = 0; mi < 8; ++mi)
        #pragma unroll
        for (int ni = 0; ni < 2; ++ni) acc[mi][ni] = (f32x4)(0.f);

    #pragma unroll
    for (int j = 0; j < 4; ++j) gload16(gA[j], &ldsA[0][rb[j]]);
    __syncthreads();

    #pragma unroll 1
    for (int ks = 0; ks < 64; ++ks) {
        int cur = ks & 1;
        if (ks + 1 < 64) {
            #pragma unroll
            for (int j = 0; j < 4; ++j) gload16(gA[j] + (ks + 1) * 64, &ldsA[cur ^ 1][rb[j]]);
        }
        int zp = z * 2 + (ks >> 5), ksz = ks & 31;
        #pragma unroll
        for (int kk = 0; kk < 2; ++kk) {
            bf16x8 af[8], bfr[2];
            #pragma unroll
            for (int ni = 0; ni < 2; ++ni) {
                int nbG = nh * 8 + w * 2 + ni;
                bfr[ni] = *(const bf16x8*)&P2[(((size_t)(zp * 16 + nbG) * 64 + ksz * 2 + kk) * 512) + lane * 8];
            }
            int chunk = kk * 4 + kgrp;
            #pragma unroll
            for (int mi = 0; mi < 8; ++mi) {
                int rl = mi * 16 + arow;
                af[mi] = *(const bf16x8*)&ldsA[cur][rl * 64 + ((chunk ^ (rl & 7)) * 8)];
            }
            #pragma unroll
            for (int mi = 0; mi < 8; ++mi)
                #pragma unroll
                for (int ni = 0; ni < 2; ++ni)
                    acc[mi][ni] = __builtin_amdgcn_mfma_f32_16x16x32_bf16(af[mi], bfr[ni], acc[mi][ni], 0, 0, 0);
        }
        __syncthreads();
    }
    // epilogue: fp32 partials
    #pragma unroll
    for (int ni = 0; ni < 2; ++ni) {
        int n = nh * 128 + w * 32 + ni * 16 + arow;
        #pragma unroll
        for (int mi = 0; mi < 8; ++mi)
            #pragma unroll
            for (int r = 0; r < 4; ++r) {
                long row = m0 + mi * 16 + kgrp * 4 + r;
                part[((size_t)z * 2048 + row) * 256 + n] = acc[mi][ni][r];
            }
    }
}

// ---------------- reduceC: out = leaky( sum_z part + b2 + sum_c bcombp ) ----------------
__global__ __launch_bounds__(256) void reduceC(const float* __restrict__ part,
                                               const float* __restrict__ bcombp,
                                               const float* __restrict__ b2v,
                                               float* __restrict__ out) {
    int l = blockIdx.x, n = threadIdx.x;
    float s = b2v[n];
    #pragma unroll
    for (int c = 0; c < 32; ++c) s += bcombp[c * 256 + n];
    #pragma unroll
    for (int z = 0; z < 8; ++z) s += part[((size_t)z * 2048 + l) * 256 + n];
    out[(size_t)l * 256 + n] = s >= 0.f ? s : 0.01f * s;
}

extern "C" void kernel_launch(void* const* d_in, const int* in_sizes, int n_in,
                              void* d_out, int out_size, void* d_ws, size_t ws_size,
                              hipStream_t stream) {
    const float* beft = (const float*)d_in[0];
    const float* Wb  = (const float*)d_in[4];
    const float* bb  = (const float*)d_in[5];
    const float* g1  = (const float*)d_in[6];
    const float* b1  = (const float*)d_in[7];
    const float* g2  = (const float*)d_in[8];
    const float* b2  = (const float*)d_in[9];
    const float* c1w = (const float*)d_in[10];
    const float* c1b = (const float*)d_in[11];
    const float* pa  = (const float*)d_in[12];
    const float* c2w = (const float*)d_in[13];
    const float* c2b = (const float*)d_in[14];
    const float* c3w = (const float*)d_in[15];
    const float* c3b = (const float*)d_in[16];
    const float* W1  = (const float*)d_in[17];
    const float* b1v = (const float*)d_in[18];
    const float* W2  = (const float*)d_in[19];
    const float* b2v = (const float*)d_in[20];
    float* out = (float*)d_out;
    char* ws = (char*)d_ws;

    // layout (early buffers all dead before gemmC writes part over them):
    float*          bpart = (float*)(ws + 0);                  // 2,097,152 [dead after attn]
    float*          cat   = (float*)(ws + 2097152);            // 6,048,000 [dead after conv]
    unsigned short* B2T   = (unsigned short*)(ws + 8388608);   // 393,216  [dead after bert]
    unsigned short* W1b   = (unsigned short*)(ws + 8781824);   // 524,288  [dead after gemmW]
    unsigned short* W2re  = (unsigned short*)(ws + 9306112);   // 4,194,304 [dead after gemmW]
    float*          part  = (float*)(ws + 0);                  // 16,777,216 [gemmC phase]
    unsigned short* P2    = (unsigned short*)(ws + 16777216);  // 16,777,216
    float*          bcombp= (float*)(ws + 33554432);           // 32,768
    unsigned short* Apool = (unsigned short*)(ws + 33587200);  // 131,072,000 -> ends 164,659,200

    prep_w<<<1792, 256, 0, stream>>>(Wb, B2T, W1, W1b);
    w2re_build<<<dim3(8, 8, 32), 256, 0, stream>>>(W2, W2re);
    bcombp_build<<<32, 256, 0, stream>>>(b1v, W2, bcombp);
    bert_mfma<<<dim3(16, 4), 256, 0, stream>>>(beft, B2T, bpart);
    window_attn<<<L_RES, 64, 0, stream>>>(bpart, bb, g1, b1, g2, b2, cat);
    gemmW<<<256, 256, 0, stream>>>(W1b, W2re, P2);
    conv_pool<<<2000, 256, 0, stream>>>(cat, c1w, c1b, pa, c2w, c2b, c3w, c3b, Apool);
    gemmC<<<256, 256, 0, stream>>>(Apool, P2, part);
    reduceC<<<L_RES, 256, 0, stream>>>(part, bcombp, b2v, out);
}

// Round 19
// 145.578 us; speedup vs baseline: 1.3214x; 1.3214x over previous
//
#include <hip/hip_runtime.h>

#define L_RES 2000
#define DF 54
#define WIN 7

typedef short bf16x8 __attribute__((ext_vector_type(8)));
typedef float f32x4 __attribute__((ext_vector_type(4)));
typedef unsigned short ushort8v __attribute__((ext_vector_type(8)));

__device__ __forceinline__ unsigned short f2bf(float f) {
    unsigned int u = __float_as_uint(f);
    unsigned int r = (u + 0x7FFFu + ((u >> 16) & 1u)) >> 16;
    return (unsigned short)r;
}
__device__ __forceinline__ float bf2f(unsigned short h) {
    return __uint_as_float(((unsigned int)h) << 16);
}
// async global->LDS, 16B per lane; LDS dest = wave-uniform base + lane*16
__device__ __forceinline__ void gload16(const unsigned short* g, unsigned short* l) {
    __builtin_amdgcn_global_load_lds(
        (const __attribute__((address_space(1))) void*)g,
        (__attribute__((address_space(3))) void*)l, 16, 0, 0);
}

// ---------------- bert stage a: split beft into A2 = [hi | lo | hi], K=3072, 2048 rows ----------------
__global__ __launch_bounds__(256) void split_beft(const float* __restrict__ beft,
                                                  unsigned short* __restrict__ A2) {
    int l = blockIdx.x;
    int t = threadIdx.x;
    unsigned short* row = A2 + (size_t)l * 3072;
    for (int k = t; k < 1024; k += 256) {
        unsigned short hi = 0, lo = 0;
        if (l < L_RES) {
            float x = beft[(size_t)l * 1024 + k];
            hi = f2bf(x);
            lo = f2bf(x - bf2f(hi));
        }
        row[k] = hi;
        row[1024 + k] = lo;
        row[2048 + k] = hi;
    }
}

// ---------------- bert stage b: B2T[64][3072]: segs {hi,hi,lo} of Wb^T ----------------
__global__ __launch_bounds__(256) void b2t_build(const float* __restrict__ Wb,
                                                 unsigned short* __restrict__ B2T) {
    int idx = blockIdx.x * 256 + threadIdx.x;   // 64*3072 = 196608
    int n = idx / 3072, col = idx % 3072;
    int seg = col >> 10, k = col & 1023;
    unsigned short r = 0;
    if (n < DF) {
        float v = Wb[(size_t)k * DF + n];
        unsigned short hi = f2bf(v);
        r = (seg < 2) ? hi : f2bf(v - bf2f(hi));
    }
    B2T[idx] = r;
}

// ---------------- bert stage c: MFMA GEMM M=2048 N=64, K-split z=4 -> fp32 partials ----------------
__global__ __launch_bounds__(256) void bert_mfma(const unsigned short* __restrict__ A2,
                                                 const unsigned short* __restrict__ B2T,
                                                 float* __restrict__ bpart) {
    __shared__ unsigned short ldsA[128 * 64];
    __shared__ unsigned short ldsB[64 * 64];
    int t = threadIdx.x, w = t >> 6, lane = t & 63;
    int m0 = blockIdx.x * 128;
    int z = blockIdx.y;                       // 4 K-slices of 768
    long koff = (long)z * 768;
    int wr = w >> 1, wc = w & 1;
    int arow = lane & 15, kgrp = lane >> 4;

    const unsigned short* aS[4]; const unsigned short* bS[2];
    int aD[4], bD[2];
    #pragma unroll
    for (int j = 0; j < 4; ++j) {
        int s = j * 256 + t, r = s >> 3, c = s & 7;
        aS[j] = A2 + koff + (size_t)(m0 + r) * 3072 + c * 8;
        aD[j] = r * 64 + ((c ^ (r & 7)) * 8);
    }
    #pragma unroll
    for (int j = 0; j < 2; ++j) {
        int s = j * 256 + t, r = s >> 3, c = s & 7;
        bS[j] = B2T + koff + (size_t)r * 3072 + c * 8;
        bD[j] = r * 64 + ((c ^ (r & 7)) * 8);
    }
    f32x4 acc[4][2];
    #pragma unroll
    for (int mi = 0; mi < 4; ++mi)
        #pragma unroll
        for (int ni = 0; ni < 2; ++ni) acc[mi][ni] = (f32x4)(0.f);

    ushort8v va[4], vb[2];
    #pragma unroll
    for (int j = 0; j < 4; ++j) va[j] = *(const ushort8v*)(aS[j]);
    #pragma unroll
    for (int j = 0; j < 2; ++j) vb[j] = *(const ushort8v*)(bS[j]);

    for (int ks = 0; ks < 12; ++ks) {
        __syncthreads();
        #pragma unroll
        for (int j = 0; j < 4; ++j) *(ushort8v*)&ldsA[aD[j]] = va[j];
        #pragma unroll
        for (int j = 0; j < 2; ++j) *(ushort8v*)&ldsB[bD[j]] = vb[j];
        __syncthreads();
        if (ks + 1 < 12) {
            #pragma unroll
            for (int j = 0; j < 4; ++j) va[j] = *(const ushort8v*)(aS[j] + (ks + 1) * 64);
            #pragma unroll
            for (int j = 0; j < 2; ++j) vb[j] = *(const ushort8v*)(bS[j] + (ks + 1) * 64);
        }
        #pragma unroll
        for (int kk = 0; kk < 2; ++kk) {
            int chunk = kk * 4 + kgrp;
            bf16x8 af[4], bfr[2];
            #pragma unroll
            for (int mi = 0; mi < 4; ++mi) {
                int rl = wr * 64 + mi * 16 + arow;
                af[mi] = *(const bf16x8*)&ldsA[rl * 64 + ((chunk ^ (rl & 7)) * 8)];
            }
            #pragma unroll
            for (int ni = 0; ni < 2; ++ni) {
                int rl = wc * 32 + ni * 16 + arow;
                bfr[ni] = *(const bf16x8*)&ldsB[rl * 64 + ((chunk ^ (rl & 7)) * 8)];
            }
            #pragma unroll
            for (int mi = 0; mi < 4; ++mi)
                #pragma unroll
                for (int ni = 0; ni < 2; ++ni)
                    acc[mi][ni] = __builtin_amdgcn_mfma_f32_16x16x32_bf16(af[mi], bfr[ni], acc[mi][ni], 0, 0, 0);
        }
    }
    #pragma unroll
    for (int ni = 0; ni < 2; ++ni) {
        int n = wc * 32 + ni * 16 + arow;
        #pragma unroll
        for (int mi = 0; mi < 4; ++mi)
            #pragma unroll
            for (int r = 0; r < 4; ++r) {
                int m = m0 + wr * 64 + mi * 16 + kgrp * 4 + r;
                bpart[((size_t)z * 2048 + m) * 64 + n] = acc[mi][ni][r];
            }
    }
}

// ---------------- bert stage d: reduce 4 partials + bias -> f (L,54) ----------------
__global__ __launch_bounds__(64) void bert_reduce(const float* __restrict__ bpart,
                                                  const float* __restrict__ bb,
                                                  float* __restrict__ f) {
    int l = blockIdx.x, n = threadIdx.x;
    if (n < DF) {
        float s = bb[n];
        #pragma unroll
        for (int z = 0; z < 4; ++z) s += bpart[((size_t)z * 2048 + l) * 64 + n];
        f[(size_t)l * DF + n] = s;
    }
}

// ---------------- window gather + attn x2 + concat: 64-thread blocks (barriers elided) ----------------
__device__ __forceinline__ void attn_layer(const float (*in)[DF], float (*out)[DF],
                                           float (*s)[WIN][WIN],
                                           const float* __restrict__ g,
                                           const float* __restrict__ b,
                                           float* mm, float* vv, int t) {
    for (int idx = t; idx < 3 * WIN * WIN; idx += 64) {
        int h = idx / 49, r = idx % 49, q = r / WIN, k = r % WIN;
        float sum = 0.f;
        #pragma unroll
        for (int d = 0; d < 18; ++d) sum = fmaf(in[q][h * 18 + d], in[k][h * 18 + d], sum);
        s[h][q][k] = sum;
    }
    __syncthreads();
    for (int idx = t; idx < 3 * WIN; idx += 64) {
        int h = idx / WIN, q = idx % WIN;
        float mx = s[h][q][0];
        #pragma unroll
        for (int k = 1; k < WIN; ++k) mx = fmaxf(mx, s[h][q][k]);
        float e[WIN], sum = 0.f;
        #pragma unroll
        for (int k = 0; k < WIN; ++k) { e[k] = expf(s[h][q][k] - mx); sum += e[k]; }
        float inv = 1.f / sum;
        #pragma unroll
        for (int k = 0; k < WIN; ++k) s[h][q][k] = e[k] * inv;
    }
    __syncthreads();
    for (int idx = t; idx < WIN * DF; idx += 64) {
        int q = idx / DF, c = idx % DF, h = c / 18;
        float sum = 0.f;
        #pragma unroll
        for (int k = 0; k < WIN; ++k) sum = fmaf(s[h][q][k], in[k][c], sum);
        out[q][c] = sum;
    }
    __syncthreads();
    for (int q = t; q < WIN; q += 64) {
        float m = 0.f;
        for (int c = 0; c < DF; ++c) m += out[q][c];
        m *= (1.f / DF);
        float v = 0.f;
        for (int c = 0; c < DF; ++c) { float d0 = out[q][c] - m; v = fmaf(d0, d0, v); }
        v *= (1.f / DF);
        mm[q] = m; vv[q] = rsqrtf(v + 1e-5f);
    }
    __syncthreads();
    for (int idx = t; idx < WIN * DF; idx += 64) {
        int q = idx / DF, c = idx % DF;
        out[q][c] = (out[q][c] - mm[q]) * vv[q] * g[c] + b[c];
    }
    __syncthreads();
}

__global__ __launch_bounds__(64) void window_attn(const float* __restrict__ f,
                                                  const float* __restrict__ g1,
                                                  const float* __restrict__ b1,
                                                  const float* __restrict__ g2,
                                                  const float* __restrict__ b2,
                                                  float* __restrict__ cat) {
    int l = blockIdx.x;
    int t = threadIdx.x;
    __shared__ float w[WIN][DF], o1[WIN][DF], o2[WIN][DF];
    __shared__ float s[3][WIN][WIN];
    __shared__ float mm[WIN], vv[WIN];
    bool boundary = (l <= WIN) || (l + WIN >= L_RES);
    for (int idx = t; idx < WIN * DF; idx += 64) {
        int j = idx / DF, d = idx % DF;
        w[j][d] = boundary ? (j == 0 ? f[(size_t)l * DF + d] : 0.f)
                           : f[(size_t)(l - 4 + j) * DF + d];
    }
    __syncthreads();
    attn_layer(w, o1, s, g1, b1, mm, vv, t);
    attn_layer(o1, o2, s, g2, b2, mm, vv, t);
    for (int idx = t; idx < WIN * DF; idx += 64) {
        int j = idx / DF, d = idx % DF;
        cat[(size_t)l * 756 + j * 108 + d] = w[j][d];
        cat[(size_t)l * 756 + j * 108 + DF + d] = o2[j][d];
    }
}

// ---------------- transpose + f32->bf16: dst[n][m], rows m>=M zero-padded (W2T) ----------------
__global__ __launch_bounds__(256) void transpose_to_bf16(const float* __restrict__ src,
                                                         unsigned short* __restrict__ dst,
                                                         int M, int N, int Mpad) {
    __shared__ float tile[32][33];
    int m0 = blockIdx.x * 32, n0 = blockIdx.y * 32;
    int c = threadIdx.x % 32, r0 = threadIdx.x / 32;
    #pragma unroll
    for (int rr = 0; rr < 4; ++rr) {
        int r = r0 + rr * 8, m = m0 + r;
        tile[r][c] = (m < M) ? src[(size_t)m * N + n0 + c] : 0.f;
    }
    __syncthreads();
    #pragma unroll
    for (int rr = 0; rr < 4; ++rr) {
        int r = r0 + rr * 8;
        dst[(size_t)(n0 + r) * Mpad + m0 + c] = f2bf(tile[c][r]);
    }
}

// ---------------- W1Tp: pack W1 into MFMA b-frag order ----------------
// P[((nb*32 + ks*2 + kk)*64 + lane)*8 + e] = bf16(W1[k][n]),
//   n = nb*16 + (lane&15), k = ks*64 + kk*32 + (lane>>4)*8 + e (0 if k>=972)
__global__ __launch_bounds__(256) void w1tp_build(const float* __restrict__ W1,
                                                  unsigned short* __restrict__ P) {
    int idx = blockIdx.x * 256 + threadIdx.x;   // 262144
    int e = idx & 7, l = (idx >> 3) & 63, g = (idx >> 9) & 31, nb = idx >> 14;
    int ks = g >> 1, kk = g & 1;
    int n = nb * 16 + (l & 15);
    int k = ks * 64 + kk * 32 + (l >> 4) * 8 + e;
    P[idx] = (k < 972) ? f2bf(W1[(size_t)k * 256 + n]) : (unsigned short)0;
}

// ---------------- conv+pool -> Apool[nt*128][1024] bf16 ----------------
__global__ __launch_bounds__(256) void conv_pool(
        const float* __restrict__ cat,
        const float* __restrict__ c1w, const float* __restrict__ c1b,
        const float* __restrict__ pa_p,
        const float* __restrict__ c2w, const float* __restrict__ c2b,
        const float* __restrict__ c3w, const float* __restrict__ c3b,
        unsigned short* __restrict__ Ap, int lbase) {
    int bid = blockIdx.x;
    int b = bid >> 2;
    int ch0 = (bid & 3) * 8;
    int l0 = lbase + b * 4;
    int t = threadIdx.x;
    __shared__ float catl[4 * 756];
    for (int i = t; i < 3024; i += 256) catl[i] = cat[(size_t)l0 * 756 + i];
    __syncthreads();
    float pa = pa_p[0];
    unsigned short* base = Ap + (size_t)b * 128 * 1024;
    int res = t >> 6, dp = t & 63;
    if (dp < 54) {
        int d0 = dp * 2;
        const float* cr = catl + res * 756;
        float colA[WIN], colB[WIN];
        #pragma unroll
        for (int h = 0; h < WIN; ++h) {
            colA[h] = cr[h * 108 + d0];
            colB[h] = cr[h * 108 + d0 + 1];
        }
        for (int c = ch0; c < ch0 + 8; ++c) {             // wave-uniform channel loop
            unsigned short* Arow = base + (size_t)(res * 32 + c) * 1024;
            {   // branch 1: k=3, prelu, pool3 -> 5 outputs
                float w0 = c1w[c * 3], w1 = c1w[c * 3 + 1], w2 = c1w[c * 3 + 2];
                float bb = c1b[c];
                float vA[WIN], vB[WIN];
                #pragma unroll
                for (int h = 0; h < WIN; ++h) {
                    float sA = bb, sB = bb;
                    if (h >= 1) { sA = fmaf(w0, colA[h - 1], sA); sB = fmaf(w0, colB[h - 1], sB); }
                    sA = fmaf(w1, colA[h], sA); sB = fmaf(w1, colB[h], sB);
                    if (h <= 5) { sA = fmaf(w2, colA[h + 1], sA); sB = fmaf(w2, colB[h + 1], sB); }
                    vA[h] = sA >= 0.f ? sA : pa * sA;
                    vB[h] = sB >= 0.f ? sB : pa * sB;
                }
                #pragma unroll
                for (int p = 0; p < 5; ++p) {
                    unsigned int ua = f2bf(fmaxf(fmaxf(vA[p], vA[p + 1]), vA[p + 2]));
                    unsigned int ub = f2bf(fmaxf(fmaxf(vB[p], vB[p + 1]), vB[p + 2]));
                    *(unsigned int*)&Arow[p * 108 + d0] = ua | (ub << 16);
                }
            }
            {   // branch 2: k=5, relu, pool5 -> 3 outputs
                float wg[5], bb = c2b[c];
                #pragma unroll
                for (int x = 0; x < 5; ++x) wg[x] = c2w[c * 5 + x];
                float vA[WIN], vB[WIN];
                #pragma unroll
                for (int h = 0; h < WIN; ++h) {
                    float sA = bb, sB = bb;
                    #pragma unroll
                    for (int x = 0; x < 5; ++x) {
                        int hh = h + x - 2;
                        if (hh >= 0 && hh <= 6) {
                            sA = fmaf(wg[x], colA[hh], sA);
                            sB = fmaf(wg[x], colB[hh], sB);
                        }
                    }
                    vA[h] = fmaxf(sA, 0.f);
                    vB[h] = fmaxf(sB, 0.f);
                }
                #pragma unroll
                for (int p = 0; p < 3; ++p) {
                    float ma = vA[p], mb = vB[p];
                    #pragma unroll
                    for (int r = 1; r < 5; ++r) { ma = fmaxf(ma, vA[p + r]); mb = fmaxf(mb, vB[p + r]); }
                    unsigned int ua = f2bf(ma), ub = f2bf(mb);
                    *(unsigned int*)&Arow[540 + p * 108 + d0] = ua | (ub << 16);
                }
            }
            {   // branch 3: k=7, relu, pool7 -> 1 output
                float wg[7], bb = c3b[c];
                #pragma unroll
                for (int x = 0; x < 7; ++x) wg[x] = c3w[c * 7 + x];
                float ma = 0.f, mb = 0.f;
                #pragma unroll
                for (int h = 0; h < WIN; ++h) {
                    float sA = bb, sB = bb;
                    #pragma unroll
                    for (int x = 0; x < 7; ++x) {
                        int hh = h + x - 3;
                        if (hh >= 0 && hh <= 6) {
                            sA = fmaf(wg[x], colA[hh], sA);
                            sB = fmaf(wg[x], colB[hh], sB);
                        }
                    }
                    ma = fmaxf(ma, sA);
                    mb = fmaxf(mb, sB);
                }
                unsigned int ua = f2bf(fmaxf(ma, 0.f)), ub = f2bf(fmaxf(mb, 0.f));
                *(unsigned int*)&Arow[864 + d0] = ua | (ub << 16);
            }
        }
    }
    // zero K-pad cols 972..1023 for this block's 32 rows (26 u32 per row)
    for (int i = t; i < 832; i += 256) {
        int r = i / 26, q = i - r * 26;           // r in 0..31
        int res2 = r >> 3, c2 = ch0 + (r & 7);
        *(unsigned int*)&base[(size_t)(res2 * 32 + c2) * 1024 + 972 + q * 2] = 0u;
    }
}

// ---------------- GEMM1 v3 (R13 config): 2-phase dbuf A (gload_lds) + packed-frag B ----------------
// 256 thr, 4 waves (1M x 4N), C[128x256]/block, K=1024 (16 K-steps of 64).
__global__ __launch_bounds__(256, 2) void gemm1k(
        const unsigned short* __restrict__ A,
        const unsigned short* __restrict__ P,
        const float* __restrict__ b1v,
        unsigned short* __restrict__ y1, long outRowBase) {
    __shared__ unsigned short ldsA[2][128 * 64];
    int t = threadIdx.x, w = t >> 6, lane = t & 63;
    long m0 = (long)blockIdx.x * 128;
    int arow = lane & 15, kgrp = lane >> 4;
    int ra = lane >> 3, cc = lane & 7;
    int csw = (cc ^ ra) * 8;                     // pre-swizzled source column

    const unsigned short* gA[4]; int rb[4];
    #pragma unroll
    for (int j = 0; j < 4; ++j) {
        int rbase = j * 32 + w * 8;
        gA[j] = A + (size_t)(m0 + rbase + ra) * 1024 + csw;
        rb[j] = rbase * 64;
    }
    f32x4 acc[8][4];
    #pragma unroll
    for (int mi = 0; mi < 8; ++mi)
        #pragma unroll
        for (int ni = 0; ni < 4; ++ni) acc[mi][ni] = (f32x4)(0.f);

    // prologue: stage tile 0
    #pragma unroll
    for (int j = 0; j < 4; ++j) gload16(gA[j], &ldsA[0][rb[j]]);
    __syncthreads();

    for (int ks = 0; ks < 16; ++ks) {
        int cur = ks & 1;
        // b-frags for both kk first (so their vmcnt waits don't drain the stage)
        bf16x8 bfr[2][4];
        #pragma unroll
        for (int kk = 0; kk < 2; ++kk)
            #pragma unroll
            for (int ni = 0; ni < 4; ++ni)
                bfr[kk][ni] = *(const bf16x8*)&P[(((size_t)(w * 4 + ni) * 32 + ks * 2 + kk) * 64 + lane) * 8];
        // issue async stage of tile ks+1 into the other buffer
        if (ks + 1 < 16) {
            #pragma unroll
            for (int j = 0; j < 4; ++j) gload16(gA[j] + (ks + 1) * 64, &ldsA[cur ^ 1][rb[j]]);
        }
        #pragma unroll
        for (int kk = 0; kk < 2; ++kk) {
            int chunk = kk * 4 + kgrp;
            bf16x8 af[8];
            #pragma unroll
            for (int mi = 0; mi < 8; ++mi) {
                int rl = mi * 16 + arow;
                af[mi] = *(const bf16x8*)&ldsA[cur][rl * 64 + ((chunk ^ (rl & 7)) * 8)];
            }
            #pragma unroll
            for (int mi = 0; mi < 8; ++mi)
                #pragma unroll
                for (int ni = 0; ni < 4; ++ni)
                    acc[mi][ni] = __builtin_amdgcn_mfma_f32_16x16x32_bf16(af[mi], bfr[kk][ni], acc[mi][ni], 0, 0, 0);
        }
        __syncthreads();     // drains stage of ks+1; syncs reads-done on ldsA[cur]
    }
    // epilogue: bias + bf16 + direct store
    #pragma unroll
    for (int ni = 0; ni < 4; ++ni) {
        int n = w * 64 + ni * 16 + arow;
        float bv = b1v[n];
        #pragma unroll
        for (int mi = 0; mi < 8; ++mi)
            #pragma unroll
            for (int r = 0; r < 4; ++r) {
                long row = m0 + mi * 16 + kgrp * 4 + r;
                y1[(outRowBase + row) * 256 + n] = f2bf(acc[mi][ni][r] + bv);
            }
    }
}

// ---------------- 8-wave tiled MFMA GEMM (GEMM2), global_load_lds staging ----------------
template<bool EPI_BF16, int ZBITS>
__global__ __launch_bounds__(512) void gemm_tile8(
        const unsigned short* __restrict__ A, long lda,
        const unsigned short* __restrict__ B, long ldb,
        int nk, const float* __restrict__ bias,
        unsigned short* __restrict__ outB, float* __restrict__ outF,
        long outRowBase) {
    __shared__ unsigned short ldsA[128 * 64];
    __shared__ unsigned short ldsB[256 * 64];
    int t = threadIdx.x, w = t >> 6, lane = t & 63;
    int bid = blockIdx.x;
    int z = bid & ((1 << ZBITS) - 1);
    long m0 = (long)(bid >> ZBITS) * 128;
    long koff = (long)z * (long)nk * 64;
    A += koff; B += koff;
    int wr = w >> 2, wc = w & 3;
    int arow = lane & 15, kgrp = lane >> 4;
    int ra = lane >> 3, cc = lane & 7;
    int csw = (cc ^ ra) * 8;

    const unsigned short* gA[2]; const unsigned short* gB[4];
    unsigned short* dA[2]; unsigned short* dB[4];
    #pragma unroll
    for (int j = 0; j < 2; ++j) {
        int rbase = j * 64 + w * 8;
        gA[j] = A + (size_t)(m0 + rbase + ra) * lda + csw;
        dA[j] = &ldsA[rbase * 64];
    }
    #pragma unroll
    for (int j = 0; j < 4; ++j) {
        int rbase = j * 64 + w * 8;
        gB[j] = B + (size_t)(rbase + ra) * ldb + csw;
        dB[j] = &ldsB[rbase * 64];
    }
    f32x4 acc[4][4];
    #pragma unroll
    for (int mi = 0; mi < 4; ++mi)
        #pragma unroll
        for (int ni = 0; ni < 4; ++ni) acc[mi][ni] = (f32x4)(0.f);

    for (int ks = 0; ks < nk; ++ks) {
        #pragma unroll
        for (int j = 0; j < 2; ++j) gload16(gA[j] + ks * 64, dA[j]);
        #pragma unroll
        for (int j = 0; j < 4; ++j) gload16(gB[j] + ks * 64, dB[j]);
        __syncthreads();
        #pragma unroll
        for (int kk = 0; kk < 2; ++kk) {
            int chunk = kk * 4 + kgrp;
            bf16x8 af[4], bfr[4];
            #pragma unroll
            for (int mi = 0; mi < 4; ++mi) {
                int rl = wr * 64 + mi * 16 + arow;
                af[mi] = *(const bf16x8*)&ldsA[rl * 64 + ((chunk ^ (rl & 7)) * 8)];
            }
            #pragma unroll
            for (int ni = 0; ni < 4; ++ni) {
                int rl = wc * 64 + ni * 16 + arow;
                bfr[ni] = *(const bf16x8*)&ldsB[rl * 64 + ((chunk ^ (rl & 7)) * 8)];
            }
            #pragma unroll
            for (int mi = 0; mi < 4; ++mi)
                #pragma unroll
                for (int ni = 0; ni < 4; ++ni)
                    acc[mi][ni] = __builtin_amdgcn_mfma_f32_16x16x32_bf16(af[mi], bfr[ni], acc[mi][ni], 0, 0, 0);
        }
        __syncthreads();
    }
    #pragma unroll
    for (int ni = 0; ni < 4; ++ni) {
        int n = wc * 64 + ni * 16 + arow;
        float bv = EPI_BF16 ? bias[n] : 0.f;
        #pragma unroll
        for (int mi = 0; mi < 4; ++mi)
            #pragma unroll
            for (int r = 0; r < 4; ++r) {
                long m = m0 + wr * 64 + mi * 16 + kgrp * 4 + r;
                if (EPI_BF16)
                    outB[(outRowBase + m) * 256 + n] = f2bf(acc[mi][ni][r] + bv);
                else
                    outF[((long)z * 2048 + m) * 256 + n] = acc[mi][ni][r];
            }
    }
}

// ---------------- reduce partials (16 K-slices) + bias + leaky ----------------
__global__ __launch_bounds__(256) void reduce2(const float* __restrict__ part,
                                               const float* __restrict__ b2v,
                                               float* __restrict__ out) {
    int l = blockIdx.x, n = threadIdx.x;
    float sum = b2v[n];
    #pragma unroll
    for (int s = 0; s < 16; ++s) sum += part[((size_t)s * 2048 + l) * 256 + n];
    out[(size_t)l * 256 + n] = sum >= 0.f ? sum : 0.01f * sum;
}

extern "C" void kernel_launch(void* const* d_in, const int* in_sizes, int n_in,
                              void* d_out, int out_size, void* d_ws, size_t ws_size,
                              hipStream_t stream) {
    const float* beft = (const float*)d_in[0];
    const float* Wb  = (const float*)d_in[4];
    const float* bb  = (const float*)d_in[5];
    const float* g1  = (const float*)d_in[6];
    const float* b1  = (const float*)d_in[7];
    const float* g2  = (const float*)d_in[8];
    const float* b2  = (const float*)d_in[9];
    const float* c1w = (const float*)d_in[10];
    const float* c1b = (const float*)d_in[11];
    const float* pa  = (const float*)d_in[12];
    const float* c2w = (const float*)d_in[13];
    const float* c2b = (const float*)d_in[14];
    const float* c3w = (const float*)d_in[15];
    const float* c3b = (const float*)d_in[16];
    const float* W1  = (const float*)d_in[17];
    const float* b1v = (const float*)d_in[18];
    const float* W2  = (const float*)d_in[19];
    const float* b2v = (const float*)d_in[20];
    float* out = (float*)d_out;
    char* ws = (char*)d_ws;

    // layout (overlays are temporally disjoint):
    float*          f    = (float*)(ws + 0);                   // 432,000 B [dead after attn]
    float*          cat  = (float*)(ws + 524288);              // 6,048,000 B [dead after conv]
    unsigned short* W1Tp = (unsigned short*)(ws + 8388608);    // 524,288 B (packed frag order)
    unsigned short* W2T  = (unsigned short*)(ws + 8912896);    // 4,194,304 B
    unsigned short* y1   = (unsigned short*)(ws + 13107200);   // 33,554,432 B
    unsigned short* A2   = (unsigned short*)(ws + 13107200);   // 12,582,912 B [bert phase, overlays y1]
    unsigned short* B2T  = (unsigned short*)(ws + 25690112);   // 393,216 B    [bert phase, within y1]
    float*          bpart= (float*)(ws + 46661632);            // 2,097,152 B  [bert phase]
    unsigned short* Ap   = (unsigned short*)(ws + 46661632);   // Apool chunk  [conv/gemm1 phase]
    float*          part = (float*)(ws + 46661632);            // 33,554,432 B [gemm2 phase]

    long avail = (long)ws_size - 46661632L;
    long tpc = avail / (128L * 1024L * 2L);
    if (tpc < 1) tpc = 1;
    if (tpc > 500) tpc = 500;

    split_beft<<<2048, 256, 0, stream>>>(beft, A2);
    b2t_build<<<768, 256, 0, stream>>>(Wb, B2T);
    bert_mfma<<<dim3(16, 4), 256, 0, stream>>>(A2, B2T, bpart);
    bert_reduce<<<L_RES, 64, 0, stream>>>(bpart, bb, f);
    window_attn<<<L_RES, 64, 0, stream>>>(f, g1, b1, g2, b2, cat);
    w1tp_build<<<1024, 256, 0, stream>>>(W1, W1Tp);
    transpose_to_bf16<<<dim3(256, 8), 256, 0, stream>>>(W2, W2T, 8192, 256, 8192);
    // y1 pad rows 2000..2047 NOT zeroed: gemm2 garbage from those A-rows lands only
    // in part rows >= 2000, which reduce2 never reads.

    for (long t0 = 0; t0 < 500; t0 += tpc) {
        long nt = (500 - t0 < tpc) ? (500 - t0) : tpc;
        conv_pool<<<(int)(nt * 4), 256, 0, stream>>>(cat, c1w, c1b, pa, c2w, c2b,
                                                     c3w, c3b, Ap, (int)(t0 * 4));
        gemm1k<<<(int)nt, 256, 0, stream>>>(Ap, W1Tp, b1v, y1, t0 * 128);
    }
    gemm_tile8<false, 4><<<256, 512, 0, stream>>>(
        y1, 8192, W2T, 8192, 8, nullptr, nullptr, part, 0);
    reduce2<<<L_RES, 256, 0, stream>>>(part, b2v, out);
}

// Round 21
// 145.243 us; speedup vs baseline: 1.3245x; 1.0023x over previous
//
#include <hip/hip_runtime.h>

#define L_RES 2000
#define DF 54
#define WIN 7

typedef short bf16x8 __attribute__((ext_vector_type(8)));
typedef float f32x4 __attribute__((ext_vector_type(4)));
typedef unsigned short ushort8v __attribute__((ext_vector_type(8)));

__device__ __forceinline__ unsigned short f2bf(float f) {
    unsigned int u = __float_as_uint(f);
    unsigned int r = (u + 0x7FFFu + ((u >> 16) & 1u)) >> 16;
    return (unsigned short)r;
}
__device__ __forceinline__ float bf2f(unsigned short h) {
    return __uint_as_float(((unsigned int)h) << 16);
}
// async global->LDS, 16B per lane; LDS dest = wave-uniform base + lane*16
__device__ __forceinline__ void gload16(const unsigned short* g, unsigned short* l) {
    __builtin_amdgcn_global_load_lds(
        (const __attribute__((address_space(1))) void*)g,
        (__attribute__((address_space(3))) void*)l, 16, 0, 0);
}

// ---------------- bert stage a: split beft into A2 = [hi | lo | hi], K=3072, 2048 rows ----------------
__global__ __launch_bounds__(256) void split_beft(const float* __restrict__ beft,
                                                  unsigned short* __restrict__ A2) {
    int l = blockIdx.x;
    int t = threadIdx.x;
    unsigned short* row = A2 + (size_t)l * 3072;
    for (int k = t; k < 1024; k += 256) {
        unsigned short hi = 0, lo = 0;
        if (l < L_RES) {
            float x = beft[(size_t)l * 1024 + k];
            hi = f2bf(x);
            lo = f2bf(x - bf2f(hi));
        }
        row[k] = hi;
        row[1024 + k] = lo;
        row[2048 + k] = hi;
    }
}

// ---------------- bert stage b: B2T[64][3072]: segs {hi,hi,lo} of Wb^T ----------------
__global__ __launch_bounds__(256) void b2t_build(const float* __restrict__ Wb,
                                                 unsigned short* __restrict__ B2T) {
    int idx = blockIdx.x * 256 + threadIdx.x;   // 64*3072 = 196608
    int n = idx / 3072, col = idx % 3072;
    int seg = col >> 10, k = col & 1023;
    unsigned short r = 0;
    if (n < DF) {
        float v = Wb[(size_t)k * DF + n];
        unsigned short hi = f2bf(v);
        r = (seg < 2) ? hi : f2bf(v - bf2f(hi));
    }
    B2T[idx] = r;
}

// ---------------- bert stage c: MFMA GEMM M=2048 N=64, K-split z=4 -> fp32 partials ----------------
__global__ __launch_bounds__(256) void bert_mfma(const unsigned short* __restrict__ A2,
                                                 const unsigned short* __restrict__ B2T,
                                                 float* __restrict__ bpart) {
    __shared__ unsigned short ldsA[128 * 64];
    __shared__ unsigned short ldsB[64 * 64];
    int t = threadIdx.x, w = t >> 6, lane = t & 63;
    int m0 = blockIdx.x * 128;
    int z = blockIdx.y;                       // 4 K-slices of 768
    long koff = (long)z * 768;
    int wr = w >> 1, wc = w & 1;
    int arow = lane & 15, kgrp = lane >> 4;

    const unsigned short* aS[4]; const unsigned short* bS[2];
    int aD[4], bD[2];
    #pragma unroll
    for (int j = 0; j < 4; ++j) {
        int s = j * 256 + t, r = s >> 3, c = s & 7;
        aS[j] = A2 + koff + (size_t)(m0 + r) * 3072 + c * 8;
        aD[j] = r * 64 + ((c ^ (r & 7)) * 8);
    }
    #pragma unroll
    for (int j = 0; j < 2; ++j) {
        int s = j * 256 + t, r = s >> 3, c = s & 7;
        bS[j] = B2T + koff + (size_t)r * 3072 + c * 8;
        bD[j] = r * 64 + ((c ^ (r & 7)) * 8);
    }
    f32x4 acc[4][2];
    #pragma unroll
    for (int mi = 0; mi < 4; ++mi)
        #pragma unroll
        for (int ni = 0; ni < 2; ++ni) acc[mi][ni] = (f32x4)(0.f);

    ushort8v va[4], vb[2];
    #pragma unroll
    for (int j = 0; j < 4; ++j) va[j] = *(const ushort8v*)(aS[j]);
    #pragma unroll
    for (int j = 0; j < 2; ++j) vb[j] = *(const ushort8v*)(bS[j]);

    for (int ks = 0; ks < 12; ++ks) {
        __syncthreads();
        #pragma unroll
        for (int j = 0; j < 4; ++j) *(ushort8v*)&ldsA[aD[j]] = va[j];
        #pragma unroll
        for (int j = 0; j < 2; ++j) *(ushort8v*)&ldsB[bD[j]] = vb[j];
        __syncthreads();
        if (ks + 1 < 12) {
            #pragma unroll
            for (int j = 0; j < 4; ++j) va[j] = *(const ushort8v*)(aS[j] + (ks + 1) * 64);
            #pragma unroll
            for (int j = 0; j < 2; ++j) vb[j] = *(const ushort8v*)(bS[j] + (ks + 1) * 64);
        }
        #pragma unroll
        for (int kk = 0; kk < 2; ++kk) {
            int chunk = kk * 4 + kgrp;
            bf16x8 af[4], bfr[2];
            #pragma unroll
            for (int mi = 0; mi < 4; ++mi) {
                int rl = wr * 64 + mi * 16 + arow;
                af[mi] = *(const bf16x8*)&ldsA[rl * 64 + ((chunk ^ (rl & 7)) * 8)];
            }
            #pragma unroll
            for (int ni = 0; ni < 2; ++ni) {
                int rl = wc * 32 + ni * 16 + arow;
                bfr[ni] = *(const bf16x8*)&ldsB[rl * 64 + ((chunk ^ (rl & 7)) * 8)];
            }
            #pragma unroll
            for (int mi = 0; mi < 4; ++mi)
                #pragma unroll
                for (int ni = 0; ni < 2; ++ni)
                    acc[mi][ni] = __builtin_amdgcn_mfma_f32_16x16x32_bf16(af[mi], bfr[ni], acc[mi][ni], 0, 0, 0);
        }
    }
    #pragma unroll
    for (int ni = 0; ni < 2; ++ni) {
        int n = wc * 32 + ni * 16 + arow;
        #pragma unroll
        for (int mi = 0; mi < 4; ++mi)
            #pragma unroll
            for (int r = 0; r < 4; ++r) {
                int m = m0 + wr * 64 + mi * 16 + kgrp * 4 + r;
                bpart[((size_t)z * 2048 + m) * 64 + n] = acc[mi][ni][r];
            }
    }
}

// ---------------- bert stage d: reduce 4 partials + bias -> f (L,54) ----------------
__global__ __launch_bounds__(64) void bert_reduce(const float* __restrict__ bpart,
                                                  const float* __restrict__ bb,
                                                  float* __restrict__ f) {
    int l = blockIdx.x, n = threadIdx.x;
    if (n < DF) {
        float s = bb[n];
        #pragma unroll
        for (int z = 0; z < 4; ++z) s += bpart[((size_t)z * 2048 + l) * 64 + n];
        f[(size_t)l * DF + n] = s;
    }
}

// ---------------- window gather + attn x2 + concat: 64-thread blocks (barriers elided) ----------------
__device__ __forceinline__ void attn_layer(const float (*in)[DF], float (*out)[DF],
                                           float (*s)[WIN][WIN],
                                           const float* __restrict__ g,
                                           const float* __restrict__ b,
                                           float* mm, float* vv, int t) {
    for (int idx = t; idx < 3 * WIN * WIN; idx += 64) {
        int h = idx / 49, r = idx % 49, q = r / WIN, k = r % WIN;
        float sum = 0.f;
        #pragma unroll
        for (int d = 0; d < 18; ++d) sum = fmaf(in[q][h * 18 + d], in[k][h * 18 + d], sum);
        s[h][q][k] = sum;
    }
    __syncthreads();
    for (int idx = t; idx < 3 * WIN; idx += 64) {
        int h = idx / WIN, q = idx % WIN;
        float mx = s[h][q][0];
        #pragma unroll
        for (int k = 1; k < WIN; ++k) mx = fmaxf(mx, s[h][q][k]);
        float e[WIN], sum = 0.f;
        #pragma unroll
        for (int k = 0; k < WIN; ++k) { e[k] = expf(s[h][q][k] - mx); sum += e[k]; }
        float inv = 1.f / sum;
        #pragma unroll
        for (int k = 0; k < WIN; ++k) s[h][q][k] = e[k] * inv;
    }
    __syncthreads();
    for (int idx = t; idx < WIN * DF; idx += 64) {
        int q = idx / DF, c = idx % DF, h = c / 18;
        float sum = 0.f;
        #pragma unroll
        for (int k = 0; k < WIN; ++k) sum = fmaf(s[h][q][k], in[k][c], sum);
        out[q][c] = sum;
    }
    __syncthreads();
    for (int q = t; q < WIN; q += 64) {
        float m = 0.f;
        for (int c = 0; c < DF; ++c) m += out[q][c];
        m *= (1.f / DF);
        float v = 0.f;
        for (int c = 0; c < DF; ++c) { float d0 = out[q][c] - m; v = fmaf(d0, d0, v); }
        v *= (1.f / DF);
        mm[q] = m; vv[q] = rsqrtf(v + 1e-5f);
    }
    __syncthreads();
    for (int idx = t; idx < WIN * DF; idx += 64) {
        int q = idx / DF, c = idx % DF;
        out[q][c] = (out[q][c] - mm[q]) * vv[q] * g[c] + b[c];
    }
    __syncthreads();
}

__global__ __launch_bounds__(64) void window_attn(const float* __restrict__ f,
                                                  const float* __restrict__ g1,
                                                  const float* __restrict__ b1,
                                                  const float* __restrict__ g2,
                                                  const float* __restrict__ b2,
                                                  float* __restrict__ cat) {
    int l = blockIdx.x;
    int t = threadIdx.x;
    __shared__ float w[WIN][DF], o1[WIN][DF], o2[WIN][DF];
    __shared__ float s[3][WIN][WIN];
    __shared__ float mm[WIN], vv[WIN];
    bool boundary = (l <= WIN) || (l + WIN >= L_RES);
    for (int idx = t; idx < WIN * DF; idx += 64) {
        int j = idx / DF, d = idx % DF;
        w[j][d] = boundary ? (j == 0 ? f[(size_t)l * DF + d] : 0.f)
                           : f[(size_t)(l - 4 + j) * DF + d];
    }
    __syncthreads();
    attn_layer(w, o1, s, g1, b1, mm, vv, t);
    attn_layer(o1, o2, s, g2, b2, mm, vv, t);
    for (int idx = t; idx < WIN * DF; idx += 64) {
        int j = idx / DF, d = idx % DF;
        cat[(size_t)l * 756 + j * 108 + d] = w[j][d];
        cat[(size_t)l * 756 + j * 108 + DF + d] = o2[j][d];
    }
}

// ---------------- transpose + f32->bf16: dst[n][m], rows m>=M zero-padded (W2T) ----------------
__global__ __launch_bounds__(256) void transpose_to_bf16(const float* __restrict__ src,
                                                         unsigned short* __restrict__ dst,
                                                         int M, int N, int Mpad) {
    __shared__ float tile[32][33];
    int m0 = blockIdx.x * 32, n0 = blockIdx.y * 32;
    int c = threadIdx.x % 32, r0 = threadIdx.x / 32;
    #pragma unroll
    for (int rr = 0; rr < 4; ++rr) {
        int r = r0 + rr * 8, m = m0 + r;
        tile[r][c] = (m < M) ? src[(size_t)m * N + n0 + c] : 0.f;
    }
    __syncthreads();
    #pragma unroll
    for (int rr = 0; rr < 4; ++rr) {
        int r = r0 + rr * 8;
        dst[(size_t)(n0 + r) * Mpad + m0 + c] = f2bf(tile[c][r]);
    }
}

// ---------------- W1Tp: pack W1 into MFMA b-frag order ----------------
// P[((nb*32 + ks*2 + kk)*64 + lane)*8 + e] = bf16(W1[k][n]),
//   n = nb*16 + (lane&15), k = ks*64 + kk*32 + (lane>>4)*8 + e (0 if k>=972)
__global__ __launch_bounds__(256) void w1tp_build(const float* __restrict__ W1,
                                                  unsigned short* __restrict__ P) {
    int idx = blockIdx.x * 256 + threadIdx.x;   // 262144
    int e = idx & 7, l = (idx >> 3) & 63, g = (idx >> 9) & 31, nb = idx >> 14;
    int ks = g >> 1, kk = g & 1;
    int n = nb * 16 + (l & 15);
    int k = ks * 64 + kk * 32 + (l >> 4) * 8 + e;
    P[idx] = (k < 972) ? f2bf(W1[(size_t)k * 256 + n]) : (unsigned short)0;
}

// ---------------- conv+pool -> Apool[nt*128][1024] bf16 ----------------
__global__ __launch_bounds__(256) void conv_pool(
        const float* __restrict__ cat,
        const float* __restrict__ c1w, const float* __restrict__ c1b,
        const float* __restrict__ pa_p,
        const float* __restrict__ c2w, const float* __restrict__ c2b,
        const float* __restrict__ c3w, const float* __restrict__ c3b,
        unsigned short* __restrict__ Ap, int lbase) {
    int bid = blockIdx.x;
    int b = bid >> 2;
    int ch0 = (bid & 3) * 8;
    int l0 = lbase + b * 4;
    int t = threadIdx.x;
    __shared__ float catl[4 * 756];
    for (int i = t; i < 3024; i += 256) catl[i] = cat[(size_t)l0 * 756 + i];
    __syncthreads();
    float pa = pa_p[0];
    unsigned short* base = Ap + (size_t)b * 128 * 1024;
    int res = t >> 6, dp = t & 63;
    if (dp < 54) {
        int d0 = dp * 2;
        const float* cr = catl + res * 756;
        float colA[WIN], colB[WIN];
        #pragma unroll
        for (int h = 0; h < WIN; ++h) {
            colA[h] = cr[h * 108 + d0];
            colB[h] = cr[h * 108 + d0 + 1];
        }
        for (int c = ch0; c < ch0 + 8; ++c) {             // wave-uniform channel loop
            unsigned short* Arow = base + (size_t)(res * 32 + c) * 1024;
            {   // branch 1: k=3, prelu, pool3 -> 5 outputs
                float w0 = c1w[c * 3], w1 = c1w[c * 3 + 1], w2 = c1w[c * 3 + 2];
                float bb = c1b[c];
                float vA[WIN], vB[WIN];
                #pragma unroll
                for (int h = 0; h < WIN; ++h) {
                    float sA = bb, sB = bb;
                    if (h >= 1) { sA = fmaf(w0, colA[h - 1], sA); sB = fmaf(w0, colB[h - 1], sB); }
                    sA = fmaf(w1, colA[h], sA); sB = fmaf(w1, colB[h], sB);
                    if (h <= 5) { sA = fmaf(w2, colA[h + 1], sA); sB = fmaf(w2, colB[h + 1], sB); }
                    vA[h] = sA >= 0.f ? sA : pa * sA;
                    vB[h] = sB >= 0.f ? sB : pa * sB;
                }
                #pragma unroll
                for (int p = 0; p < 5; ++p) {
                    unsigned int ua = f2bf(fmaxf(fmaxf(vA[p], vA[p + 1]), vA[p + 2]));
                    unsigned int ub = f2bf(fmaxf(fmaxf(vB[p], vB[p + 1]), vB[p + 2]));
                    *(unsigned int*)&Arow[p * 108 + d0] = ua | (ub << 16);
                }
            }
            {   // branch 2: k=5, relu, pool5 -> 3 outputs
                float wg[5], bb = c2b[c];
                #pragma unroll
                for (int x = 0; x < 5; ++x) wg[x] = c2w[c * 5 + x];
                float vA[WIN], vB[WIN];
                #pragma unroll
                for (int h = 0; h < WIN; ++h) {
                    float sA = bb, sB = bb;
                    #pragma unroll
                    for (int x = 0; x < 5; ++x) {
                        int hh = h + x - 2;
                        if (hh >= 0 && hh <= 6) {
                            sA = fmaf(wg[x], colA[hh], sA);
                            sB = fmaf(wg[x], colB[hh], sB);
                        }
                    }
                    vA[h] = fmaxf(sA, 0.f);
                    vB[h] = fmaxf(sB, 0.f);
                }
                #pragma unroll
                for (int p = 0; p < 3; ++p) {
                    float ma = vA[p], mb = vB[p];
                    #pragma unroll
                    for (int r = 1; r < 5; ++r) { ma = fmaxf(ma, vA[p + r]); mb = fmaxf(mb, vB[p + r]); }
                    unsigned int ua = f2bf(ma), ub = f2bf(mb);
                    *(unsigned int*)&Arow[540 + p * 108 + d0] = ua | (ub << 16);
                }
            }
            {   // branch 3: k=7, relu, pool7 -> 1 output
                float wg[7], bb = c3b[c];
                #pragma unroll
                for (int x = 0; x < 7; ++x) wg[x] = c3w[c * 7 + x];
                float ma = 0.f, mb = 0.f;
                #pragma unroll
                for (int h = 0; h < WIN; ++h) {
                    float sA = bb, sB = bb;
                    #pragma unroll
                    for (int x = 0; x < 7; ++x) {
                        int hh = h + x - 3;
                        if (hh >= 0 && hh <= 6) {
                            sA = fmaf(wg[x], colA[hh], sA);
                            sB = fmaf(wg[x], colB[hh], sB);
                        }
                    }
                    ma = fmaxf(ma, sA);
                    mb = fmaxf(mb, sB);
                }
                unsigned int ua = f2bf(fmaxf(ma, 0.f)), ub = f2bf(fmaxf(mb, 0.f));
                *(unsigned int*)&Arow[864 + d0] = ua | (ub << 16);
            }
        }
    }
    // zero K-pad cols 972..1023 for this block's 32 rows (26 u32 per row)
    for (int i = t; i < 832; i += 256) {
        int r = i / 26, q = i - r * 26;           // r in 0..31
        int res2 = r >> 3, c2 = ch0 + (r & 7);
        *(unsigned int*)&base[(size_t)(res2 * 32 + c2) * 1024 + 972 + q * 2] = 0u;
    }
}

// ---------------- GEMM1 v3 (R13 config, proven stable): 2-phase dbuf A + packed-frag B ----------------
// 256 thr, 4 waves (1M x 4N), C[128x256]/block, K=1024 (16 K-steps of 64).
__global__ __launch_bounds__(256, 2) void gemm1k(
        const unsigned short* __restrict__ A,
        const unsigned short* __restrict__ P,
        const float* __restrict__ b1v,
        unsigned short* __restrict__ y1, long outRowBase) {
    __shared__ unsigned short ldsA[2][128 * 64];
    int t = threadIdx.x, w = t >> 6, lane = t & 63;
    long m0 = (long)blockIdx.x * 128;
    int arow = lane & 15, kgrp = lane >> 4;
    int ra = lane >> 3, cc = lane & 7;
    int csw = (cc ^ ra) * 8;                     // pre-swizzled source column

    const unsigned short* gA[4]; int rb[4];
    #pragma unroll
    for (int j = 0; j < 4; ++j) {
        int rbase = j * 32 + w * 8;
        gA[j] = A + (size_t)(m0 + rbase + ra) * 1024 + csw;
        rb[j] = rbase * 64;
    }
    f32x4 acc[8][4];
    #pragma unroll
    for (int mi = 0; mi < 8; ++mi)
        #pragma unroll
        for (int ni = 0; ni < 4; ++ni) acc[mi][ni] = (f32x4)(0.f);

    // prologue: stage tile 0
    #pragma unroll
    for (int j = 0; j < 4; ++j) gload16(gA[j], &ldsA[0][rb[j]]);
    __syncthreads();

    for (int ks = 0; ks < 16; ++ks) {
        int cur = ks & 1;
        // b-frags for both kk first (so their vmcnt waits don't drain the stage)
        bf16x8 bfr[2][4];
        #pragma unroll
        for (int kk = 0; kk < 2; ++kk)
            #pragma unroll
            for (int ni = 0; ni < 4; ++ni)
                bfr[kk][ni] = *(const bf16x8*)&P[(((size_t)(w * 4 + ni) * 32 + ks * 2 + kk) * 64 + lane) * 8];
        // issue async stage of tile ks+1 into the other buffer
        if (ks + 1 < 16) {
            #pragma unroll
            for (int j = 0; j < 4; ++j) gload16(gA[j] + (ks + 1) * 64, &ldsA[cur ^ 1][rb[j]]);
        }
        #pragma unroll
        for (int kk = 0; kk < 2; ++kk) {
            int chunk = kk * 4 + kgrp;
            bf16x8 af[8];
            #pragma unroll
            for (int mi = 0; mi < 8; ++mi) {
                int rl = mi * 16 + arow;
                af[mi] = *(const bf16x8*)&ldsA[cur][rl * 64 + ((chunk ^ (rl & 7)) * 8)];
            }
            #pragma unroll
            for (int mi = 0; mi < 8; ++mi)
                #pragma unroll
                for (int ni = 0; ni < 4; ++ni)
                    acc[mi][ni] = __builtin_amdgcn_mfma_f32_16x16x32_bf16(af[mi], bfr[kk][ni], acc[mi][ni], 0, 0, 0);
        }
        __syncthreads();     // drains stage of ks+1; syncs reads-done on ldsA[cur]
    }
    // epilogue: bias + bf16 + direct store
    #pragma unroll
    for (int ni = 0; ni < 4; ++ni) {
        int n = w * 64 + ni * 16 + arow;
        float bv = b1v[n];
        #pragma unroll
        for (int mi = 0; mi < 8; ++mi)
            #pragma unroll
            for (int r = 0; r < 4; ++r) {
                long row = m0 + mi * 16 + kgrp * 4 + r;
                y1[(outRowBase + row) * 256 + n] = f2bf(acc[mi][ni][r] + bv);
            }
    }
}

// ---------------- 8-wave tiled MFMA GEMM (GEMM2), global_load_lds staging ----------------
template<bool EPI_BF16, int ZBITS>
__global__ __launch_bounds__(512) void gemm_tile8(
        const unsigned short* __restrict__ A, long lda,
        const unsigned short* __restrict__ B, long ldb,
        int nk, const float* __restrict__ bias,
        unsigned short* __restrict__ outB, float* __restrict__ outF,
        long outRowBase) {
    __shared__ unsigned short ldsA[128 * 64];
    __shared__ unsigned short ldsB[256 * 64];
    int t = threadIdx.x, w = t >> 6, lane = t & 63;
    int bid = blockIdx.x;
    int z = bid & ((1 << ZBITS) - 1);
    long m0 = (long)(bid >> ZBITS) * 128;
    long koff = (long)z * (long)nk * 64;
    A += koff; B += koff;
    int wr = w >> 2, wc = w & 3;
    int arow = lane & 15, kgrp = lane >> 4;
    int ra = lane >> 3, cc = lane & 7;
    int csw = (cc ^ ra) * 8;

    const unsigned short* gA[2]; const unsigned short* gB[4];
    unsigned short* dA[2]; unsigned short* dB[4];
    #pragma unroll
    for (int j = 0; j < 2; ++j) {
        int rbase = j * 64 + w * 8;
        gA[j] = A + (size_t)(m0 + rbase + ra) * lda + csw;
        dA[j] = &ldsA[rbase * 64];
    }
    #pragma unroll
    for (int j = 0; j < 4; ++j) {
        int rbase = j * 64 + w * 8;
        gB[j] = B + (size_t)(rbase + ra) * ldb + csw;
        dB[j] = &ldsB[rbase * 64];
    }
    f32x4 acc[4][4];
    #pragma unroll
    for (int mi = 0; mi < 4; ++mi)
        #pragma unroll
        for (int ni = 0; ni < 4; ++ni) acc[mi][ni] = (f32x4)(0.f);

    for (int ks = 0; ks < nk; ++ks) {
        #pragma unroll
        for (int j = 0; j < 2; ++j) gload16(gA[j] + ks * 64, dA[j]);
        #pragma unroll
        for (int j = 0; j < 4; ++j) gload16(gB[j] + ks * 64, dB[j]);
        __syncthreads();
        #pragma unroll
        for (int kk = 0; kk < 2; ++kk) {
            int chunk = kk * 4 + kgrp;
            bf16x8 af[4], bfr[4];
            #pragma unroll
            for (int mi = 0; mi < 4; ++mi) {
                int rl = wr * 64 + mi * 16 + arow;
                af[mi] = *(const bf16x8*)&ldsA[rl * 64 + ((chunk ^ (rl & 7)) * 8)];
            }
            #pragma unroll
            for (int ni = 0; ni < 4; ++ni) {
                int rl = wc * 64 + ni * 16 + arow;
                bfr[ni] = *(const bf16x8*)&ldsB[rl * 64 + ((chunk ^ (rl & 7)) * 8)];
            }
            #pragma unroll
            for (int mi = 0; mi < 4; ++mi)
                #pragma unroll
                for (int ni = 0; ni < 4; ++ni)
                    acc[mi][ni] = __builtin_amdgcn_mfma_f32_16x16x32_bf16(af[mi], bfr[ni], acc[mi][ni], 0, 0, 0);
        }
        __syncthreads();
    }
    #pragma unroll
    for (int ni = 0; ni < 4; ++ni) {
        int n = wc * 64 + ni * 16 + arow;
        float bv = EPI_BF16 ? bias[n] : 0.f;
        #pragma unroll
        for (int mi = 0; mi < 4; ++mi)
            #pragma unroll
            for (int r = 0; r < 4; ++r) {
                long m = m0 + wr * 64 + mi * 16 + kgrp * 4 + r;
                if (EPI_BF16)
                    outB[(outRowBase + m) * 256 + n] = f2bf(acc[mi][ni][r] + bv);
                else
                    outF[((long)z * 2048 + m) * 256 + n] = acc[mi][ni][r];
            }
    }
}

// ---------------- reduce partials (16 K-slices) + bias + leaky ----------------
__global__ __launch_bounds__(256) void reduce2(const float* __restrict__ part,
                                               const float* __restrict__ b2v,
                                               float* __restrict__ out) {
    int l = blockIdx.x, n = threadIdx.x;
    float sum = b2v[n];
    #pragma unroll
    for (int s = 0; s < 16; ++s) sum += part[((size_t)s * 2048 + l) * 256 + n];
    out[(size_t)l * 256 + n] = sum >= 0.f ? sum : 0.01f * sum;
}

extern "C" void kernel_launch(void* const* d_in, const int* in_sizes, int n_in,
                              void* d_out, int out_size, void* d_ws, size_t ws_size,
                              hipStream_t stream) {
    const float* beft = (const float*)d_in[0];
    const float* Wb  = (const float*)d_in[4];
    const float* bb  = (const float*)d_in[5];
    const float* g1  = (const float*)d_in[6];
    const float* b1  = (const float*)d_in[7];
    const float* g2  = (const float*)d_in[8];
    const float* b2  = (const float*)d_in[9];
    const float* c1w = (const float*)d_in[10];
    const float* c1b = (const float*)d_in[11];
    const float* pa  = (const float*)d_in[12];
    const float* c2w = (const float*)d_in[13];
    const float* c2b = (const float*)d_in[14];
    const float* c3w = (const float*)d_in[15];
    const float* c3b = (const float*)d_in[16];
    const float* W1  = (const float*)d_in[17];
    const float* b1v = (const float*)d_in[18];
    const float* W2  = (const float*)d_in[19];
    const float* b2v = (const float*)d_in[20];
    float* out = (float*)d_out;
    char* ws = (char*)d_ws;

    // layout (overlays are temporally disjoint):
    float*          f    = (float*)(ws + 0);                   // 432,000 B [dead after attn]
    float*          cat  = (float*)(ws + 524288);              // 6,048,000 B [dead after conv]
    unsigned short* W1Tp = (unsigned short*)(ws + 8388608);    // 524,288 B (packed frag order)
    unsigned short* W2T  = (unsigned short*)(ws + 8912896);    // 4,194,304 B
    unsigned short* y1   = (unsigned short*)(ws + 13107200);   // 33,554,432 B
    unsigned short* A2   = (unsigned short*)(ws + 13107200);   // 12,582,912 B [bert phase, overlays y1]
    unsigned short* B2T  = (unsigned short*)(ws + 25690112);   // 393,216 B    [bert phase, within y1]
    float*          bpart= (float*)(ws + 46661632);            // 2,097,152 B  [bert phase]
    unsigned short* Ap   = (unsigned short*)(ws + 46661632);   // Apool chunk  [conv/gemm1 phase]
    float*          part = (float*)(ws + 46661632);            // 33,554,432 B [gemm2 phase]

    long avail = (long)ws_size - 46661632L;
    long tpc = avail / (128L * 1024L * 2L);
    if (tpc < 1) tpc = 1;
    if (tpc > 500) tpc = 500;

    split_beft<<<2048, 256, 0, stream>>>(beft, A2);
    b2t_build<<<768, 256, 0, stream>>>(Wb, B2T);
    bert_mfma<<<dim3(16, 4), 256, 0, stream>>>(A2, B2T, bpart);
    bert_reduce<<<L_RES, 64, 0, stream>>>(bpart, bb, f);
    window_attn<<<L_RES, 64, 0, stream>>>(f, g1, b1, g2, b2, cat);
    w1tp_build<<<1024, 256, 0, stream>>>(W1, W1Tp);
    transpose_to_bf16<<<dim3(256, 8), 256, 0, stream>>>(W2, W2T, 8192, 256, 8192);
    // y1 pad rows 2000..2047 NOT zeroed: gemm2 garbage from those A-rows lands only
    // in part rows >= 2000, which reduce2 never reads.

    for (long t0 = 0; t0 < 500; t0 += tpc) {
        long nt = (500 - t0 < tpc) ? (500 - t0) : tpc;
        conv_pool<<<(int)(nt * 4), 256, 0, stream>>>(cat, c1w, c1b, pa, c2w, c2b,
                                                     c3w, c3b, Ap, (int)(t0 * 4));
        gemm1k<<<(int)nt, 256, 0, stream>>>(Ap, W1Tp, b1v, y1, t0 * 128);
    }
    gemm_tile8<false, 4><<<256, 512, 0, stream>>>(
        y1, 8192, W2T, 8192, 8, nullptr, nullptr, part, 0);
    reduce2<<<L_RES, 256, 0, stream>>>(part, b2v, out);
}